// Round 1
// baseline (23.443 us; speedup 1.0000x reference)
//
#include <hip/hip_runtime.h>

#define BB 8
#define SS 64
#define AA 9
#define MM 64
#define NN (SS * SS * AA)  // 36864 boxes per batch image

// One thread per box. Block = 256 threads; N % 256 == 0 -> 144 blocks per batch.
__global__ __launch_bounds__(256) void frcnn_head_kernel(
    const float* __restrict__ rpn_off,   // (B, S, S, A, 4) flat = (B, N, 4)
    const float* __restrict__ frc_off,   // (B, N, 4)
    const float* __restrict__ gt,        // (B, M, 4)
    const float* __restrict__ anchor_h,  // (A,)
    const float* __restrict__ anchor_w,  // (A,)
    float* __restrict__ out)
{
    __shared__ float gt_s[MM * 4];   // gt boxes for this batch image
    __shared__ float area_s[MM];     // gt areas
    __shared__ float ah_s[AA];
    __shared__ float aw_s[AA];

    const int blocks_per_b = NN / 256;          // 144
    const int b     = blockIdx.x / blocks_per_b;
    const int chunk = blockIdx.x % blocks_per_b;
    const int tid   = threadIdx.x;
    const int i     = chunk * 256 + tid;        // box index within batch, < N

    // Stage GT boxes + anchors into LDS (1 KB + 36 B + 36 B).
    if (tid < MM * 4) gt_s[tid] = gt[(size_t)b * MM * 4 + tid];
    if (tid < AA) { ah_s[tid] = anchor_h[tid]; aw_s[tid] = anchor_w[tid]; }
    __syncthreads();
    if (tid < MM) {
        const float gx1 = gt_s[tid * 4 + 0], gy1 = gt_s[tid * 4 + 1];
        const float gx2 = gt_s[tid * 4 + 2], gy2 = gt_s[tid * 4 + 3];
        area_s[tid] = (gx2 - gx1) * (gy2 - gy1);
    }
    __syncthreads();

    // ---- 1. decode RPN box ----
    const int a_idx = i % AA;
    const int xy    = i / AA;
    const int gx    = xy % SS;   // second S dim -> x
    const int gy    = xy / SS;   // first  S dim -> y
    const float stride = 800.0f / (float)SS;  // 12.5
    const float acx = ((float)gx + 0.5f) * stride;
    const float acy = ((float)gy + 0.5f) * stride;

    const float4 t = ((const float4*)rpn_off)[(size_t)b * NN + i];
    const float aw = aw_s[a_idx];
    const float ah = ah_s[a_idx];

    const float pcx = acx + t.x * aw;
    const float pcy = acy + t.y * ah;
    const float pw  = aw * expf(t.z);
    const float ph  = ah * expf(t.w);

    const float bx1 = fminf(fmaxf(pcx - 0.5f * pw, 0.0f), 800.0f);
    const float by1 = fminf(fmaxf(pcy - 0.5f * ph, 0.0f), 800.0f);
    const float bx2 = fminf(fmaxf(pcx + 0.5f * pw, 0.0f), 800.0f);
    const float by2 = fminf(fmaxf(pcy + 0.5f * ph, 0.0f), 800.0f);

    // ---- 2. IoU max + first-argmax over 64 GT boxes ----
    const float area = (bx2 - bx1) * (by2 - by1);
    float best  = -1.0f;
    int   bestj = 0;
    #pragma unroll 8
    for (int j = 0; j < MM; ++j) {
        const float gx1 = gt_s[j * 4 + 0], gy1 = gt_s[j * 4 + 1];
        const float gx2 = gt_s[j * 4 + 2], gy2 = gt_s[j * 4 + 3];
        const float ix1 = fmaxf(bx1, gx1);
        const float iy1 = fmaxf(by1, gy1);
        const float ix2 = fminf(bx2, gx2);
        const float iy2 = fminf(by2, gy2);
        const float iw = fmaxf(ix2 - ix1, 0.0f);
        const float ih = fmaxf(iy2 - iy1, 0.0f);
        const float inter = iw * ih;
        const float iou = inter / (area + area_s[j] - inter + 1e-9f);
        if (iou > best) { best = iou; bestj = j; }  // strict > == jnp first-argmax
    }

    // ---- 3. refine with fast-rcnn offsets ----
    const float4 f = ((const float4*)frc_off)[(size_t)b * NN + i];
    const float w = bx2 - bx1;
    const float h = by2 - by1;
    const float rx1 = f.x * w + bx1;
    const float ry1 = f.y * h + by1;
    const float rx2 = rx1 + expf(f.z) * w;
    const float ry2 = ry1 + expf(f.w) * h;

    // ---- 4. write outputs (tuple concatenated flat) ----
    const size_t BN  = (size_t)BB * NN;
    const size_t o1  = BN * 4;        // is_foreground
    const size_t o2  = o1 + BN;       // best_gt_index
    const size_t o3  = o2 + BN;       // refined_bbox
    const size_t idx = (size_t)b * NN + i;

    ((float4*)out)[idx] = make_float4(bx1, by1, bx2, by2);
    out[o1 + idx] = (best > 0.5f) ? 1.0f : 0.0f;
    out[o2 + idx] = (float)bestj;
    ((float4*)(out + o3))[idx] = make_float4(rx1, ry1, rx2, ry2);
}

extern "C" void kernel_launch(void* const* d_in, const int* in_sizes, int n_in,
                              void* d_out, int out_size, void* d_ws, size_t ws_size,
                              hipStream_t stream) {
    const float* rpn_off  = (const float*)d_in[0];
    const float* frc_off  = (const float*)d_in[1];
    const float* gt       = (const float*)d_in[2];
    const float* anchor_h = (const float*)d_in[3];
    const float* anchor_w = (const float*)d_in[4];
    float* out = (float*)d_out;

    const int grid = BB * (NN / 256);  // 8 * 144 = 1152 blocks
    frcnn_head_kernel<<<grid, 256, 0, stream>>>(rpn_off, frc_off, gt,
                                                anchor_h, anchor_w, out);
}

// Round 2
// 20.925 us; speedup vs baseline: 1.1203x; 1.1203x over previous
//
#include <hip/hip_runtime.h>

#define BB 8
#define SS 64
#define AA 9
#define MM 64
#define NN (SS * SS * AA)  // 36864 boxes per batch image

// Two boxes per thread (i and i+256). Block = 256 threads -> 512 boxes/block.
// NN % 512 == 0 -> 72 blocks per batch image.
__global__ __launch_bounds__(256) void frcnn_head_kernel(
    const float* __restrict__ rpn_off,   // (B, N, 4)
    const float* __restrict__ frc_off,   // (B, N, 4)
    const float* __restrict__ gt,        // (B, M, 4)
    const float* __restrict__ anchor_h,  // (A,)
    const float* __restrict__ anchor_w,  // (A,)
    float* __restrict__ out)
{
    __shared__ float gt_s[MM * 4];
    __shared__ float area_s[MM];
    __shared__ float ah_s[AA];
    __shared__ float aw_s[AA];

    const int blocks_per_b = NN / 512;          // 72
    const int b     = blockIdx.x / blocks_per_b;
    const int chunk = blockIdx.x % blocks_per_b;
    const int tid   = threadIdx.x;
    const int i0    = chunk * 512 + tid;        // first box
    const int i1    = i0 + 256;                 // second box

    if (tid < MM * 4) gt_s[tid] = gt[(size_t)b * MM * 4 + tid];
    if (tid < AA) { ah_s[tid] = anchor_h[tid]; aw_s[tid] = anchor_w[tid]; }
    __syncthreads();
    if (tid < MM) {
        const float gx1 = gt_s[tid * 4 + 0], gy1 = gt_s[tid * 4 + 1];
        const float gx2 = gt_s[tid * 4 + 2], gy2 = gt_s[tid * 4 + 3];
        area_s[tid] = (gx2 - gx1) * (gy2 - gy1);
    }
    __syncthreads();

    // ---- 1. decode both RPN boxes ----
    const float stride = 800.0f / (float)SS;  // 12.5
    float bx1[2], by1[2], bx2[2], by2[2], area[2];
    const int ii[2] = { i0, i1 };
    #pragma unroll
    for (int k = 0; k < 2; ++k) {
        const int i     = ii[k];
        const int a_idx = i % AA;
        const int xy    = i / AA;
        const int gx    = xy % SS;
        const int gy    = xy / SS;
        const float acx = ((float)gx + 0.5f) * stride;
        const float acy = ((float)gy + 0.5f) * stride;

        const float4 t = ((const float4*)rpn_off)[(size_t)b * NN + i];
        const float aw = aw_s[a_idx];
        const float ah = ah_s[a_idx];

        const float pcx = acx + t.x * aw;
        const float pcy = acy + t.y * ah;
        const float pw  = aw * expf(t.z);
        const float ph  = ah * expf(t.w);

        bx1[k] = fminf(fmaxf(pcx - 0.5f * pw, 0.0f), 800.0f);
        by1[k] = fminf(fmaxf(pcy - 0.5f * ph, 0.0f), 800.0f);
        bx2[k] = fminf(fmaxf(pcx + 0.5f * pw, 0.0f), 800.0f);
        by2[k] = fminf(fmaxf(pcy + 0.5f * ph, 0.0f), 800.0f);
        area[k] = (bx2[k] - bx1[k]) * (by2[k] - by1[k]);
    }

    // ---- 2. max/first-argmax IoU, division-free (fraction compare) ----
    // iou_j > best  <=>  inter_j * best_den > best_num * den_j   (dens > 0)
    float bnum[2] = { -1.0f, -1.0f };
    float bden[2] = {  1.0f,  1.0f };
    int   bj[2]   = {  0, 0 };
    #pragma unroll 4
    for (int j = 0; j < MM; ++j) {
        const float gx1 = gt_s[j * 4 + 0], gy1 = gt_s[j * 4 + 1];
        const float gx2 = gt_s[j * 4 + 2], gy2 = gt_s[j * 4 + 3];
        const float ga  = area_s[j];
        #pragma unroll
        for (int k = 0; k < 2; ++k) {
            const float ix1 = fmaxf(bx1[k], gx1);
            const float iy1 = fmaxf(by1[k], gy1);
            const float ix2 = fminf(bx2[k], gx2);
            const float iy2 = fminf(by2[k], gy2);
            const float iw  = fmaxf(ix2 - ix1, 0.0f);
            const float ih  = fmaxf(iy2 - iy1, 0.0f);
            const float inter = iw * ih;
            const float den   = area[k] + ga - inter + 1e-9f;
            if (inter * bden[k] > bnum[k] * den) {
                bnum[k] = inter; bden[k] = den; bj[k] = j;
            }
        }
    }

    // ---- 3/4. refine + write outputs ----
    const size_t BN = (size_t)BB * NN;
    const size_t o1 = BN * 4;       // is_foreground
    const size_t o2 = o1 + BN;      // best_gt_index
    const size_t o3 = o2 + BN;      // refined_bbox

    #pragma unroll
    for (int k = 0; k < 2; ++k) {
        const int i = ii[k];
        const size_t idx = (size_t)b * NN + i;

        const float4 f = ((const float4*)frc_off)[(size_t)b * NN + i];
        const float w = bx2[k] - bx1[k];
        const float h = by2[k] - by1[k];
        const float rx1 = f.x * w + bx1[k];
        const float ry1 = f.y * h + by1[k];
        const float rx2 = rx1 + expf(f.z) * w;
        const float ry2 = ry1 + expf(f.w) * h;

        ((float4*)out)[idx] = make_float4(bx1[k], by1[k], bx2[k], by2[k]);
        // best_iou > 0.5  <=>  inter > 0.5 * den   (den > 0)
        out[o1 + idx] = (bnum[k] > 0.5f * bden[k]) ? 1.0f : 0.0f;
        out[o2 + idx] = (float)bj[k];
        ((float4*)(out + o3))[idx] = make_float4(rx1, ry1, rx2, ry2);
    }
}

extern "C" void kernel_launch(void* const* d_in, const int* in_sizes, int n_in,
                              void* d_out, int out_size, void* d_ws, size_t ws_size,
                              hipStream_t stream) {
    const float* rpn_off  = (const float*)d_in[0];
    const float* frc_off  = (const float*)d_in[1];
    const float* gt       = (const float*)d_in[2];
    const float* anchor_h = (const float*)d_in[3];
    const float* anchor_w = (const float*)d_in[4];
    float* out = (float*)d_out;

    const int grid = BB * (NN / 512);  // 8 * 72 = 576 blocks
    frcnn_head_kernel<<<grid, 256, 0, stream>>>(rpn_off, frc_off, gt,
                                                anchor_h, anchor_w, out);
}